// Round 16
// baseline (193.734 us; speedup 1.0000x reference)
//
#include <hip/hip_runtime.h>

#define BATCH   1024
#define MSIZE   65536
#define KDIM    256
#define CHOOSEK 128
#define SELK    160        // superset floor (margin vs bf16 screening error, proven r2-r15)
// Three mask thresholds on the u8-scale screened score x = sim*KSC + L[n]:
// cnt(>=156)~307+-17, cnt(>=160)~230+-15, cnt(>=164)~172+-13 (model validated at
// 128 -> ~1650-2800 obs, 152 -> ~410). Select walks the HIGHEST level with
// SELK <= cnt <= 1024: |{x>=T}| >= SELK ==> {x>=T} superset of screened-top-SELK
// superset of exact top-128; extra candidates never alter the exact-rescored top-128.
#define T0  156.0f
#define T1  160.0f
#define T2  164.0f
#define BETA    1e-8f
#define ALPHA   0.5f
#define KSC  425.0f
#define KOFF 7.2f
#define LVLW ((size_t)1024 * 1024)   // u64 words per mask level (512 nt x 2 wq x 1024 rows)

typedef short bf16x8 __attribute__((ext_vector_type(8)));
typedef float f32x4  __attribute__((ext_vector_type(4)));

__device__ inline unsigned int pack2bf(float a, float b) {   // RNE fp32->bf16 pair
    unsigned int ua = __float_as_uint(a);
    unsigned int ub = __float_as_uint(b);
    ua += 0x7fffu + ((ua >> 16) & 1u);
    ub += 0x7fffu + ((ub >> 16) & 1u);
    return (ua >> 16) | (ub & 0xffff0000u);
}

// -------------------------------------------------------------------------
// Kernel 0: one-time preprocessing.
//  blocks [0,8192):    key fp32 -> bf16 in B-FRAGMENT order (kbf): frag
//     f = ((nt*2+wnh)*8+ks)*4+i, lane l holds key row nt*128+wnh*64+i*16+(l&15),
//     cols ks*32+(l>>4)*8 (16B). Score reads each B-fragment as ONE coalesced
//     1KB dwordx4/wave -> NO LDS staging, NO barriers in the GEMM.
//  blocks [8192,8320): q fp32 -> bf16 A-fragment order (r7 layout, bt in [0,8)).
//  blocks [8320,8576): L[n] = (log(hist[n]+BETA)+KOFF)*KSC.
// -------------------------------------------------------------------------
__global__ __launch_bounds__(256)
void convert_kernel(const float* __restrict__ q, const float* __restrict__ key,
                    const float* __restrict__ hist,
                    unsigned short* __restrict__ qs, unsigned short* __restrict__ kbf,
                    float* __restrict__ Ltab)
{
    const int bid = blockIdx.x, tid = threadIdx.x;
    if (bid < 8192) {                       // key -> B-fragment order
        const int t = bid * 256 + tid;      // [0, 2M) : frag = t>>6, lane = t&63
        const int l = t & 63, f = t >> 6;
        const int i = f & 3, ks = (f >> 2) & 7, wnh = (f >> 5) & 1, nt = f >> 6;
        const int row = nt * 128 + wnh * 64 + i * 16 + (l & 15);
        const int col = ks * 32 + (l >> 4) * 8;
        const float* src = key + (size_t)row * KDIM + col;
        float4 a = *(const float4*)src, b = *(const float4*)(src + 4);
        ((uint4*)kbf)[t] = make_uint4(pack2bf(a.x, a.y), pack2bf(a.z, a.w),
                                      pack2bf(b.x, b.y), pack2bf(b.z, b.w));
    } else if (bid < 8320) {                // q -> A-fragment order (128-row tiles)
        const int f = (bid - 8192) * 256 + tid;
        const int l = f & 63, j = (f >> 6) & 3, ks = (f >> 8) & 7;
        const int wmg = (f >> 11) & 1, bt = f >> 12;       // bt in [0,8)
        const int r = bt * 128 + wmg * 64 + j * 16 + (l & 15);
        const int c = ks * 32 + (l >> 4) * 8;
        const float* src = q + (size_t)r * KDIM + c;
        float4 a = *(const float4*)src, b = *(const float4*)(src + 4);
        ((uint4*)qs)[f] = make_uint4(pack2bf(a.x, a.y), pack2bf(a.z, a.w),
                                     pack2bf(b.x, b.y), pack2bf(b.z, b.w));
    } else {                                // L table
        const int n = (bid - 8320) * 256 + tid;
        Ltab[n] = (logf(hist[n] + BETA) + KOFF) * KSC;
    }
}

// -------------------------------------------------------------------------
// Kernel 1: BARRIER-FREE bf16 screening GEMM. Both operands pre-swizzled into
// fragment-ordered global tables (qsw 512KB L2-resident; kbf 32MB — with
// XCD-grouped n-tiles each XCD's slice = 64 nt x 64KB = 4MB = its L2).
// 256 thr / 4 waves / 128x128 tile / grid 4096. Per K-step per wave: 8
// coalesced 1KB fragment loads (double-buffered regs, 1-step-ahead) + 16 MFMA.
// No LDS, no s_barrier, no manual vmcnt — compiler schedules register loads.
// Epilogue: x = fma(acc,KSC,L[n]); three threshold masks, shfl-OR per 4-lane
// group; SoA level-major mask layout -> 16-lane x 8B FULL-LINE stores.
// -------------------------------------------------------------------------
__global__ __launch_bounds__(256)
void score_kernel(const unsigned short* __restrict__ qs,
                  const unsigned short* __restrict__ kbf,
                  const float* __restrict__ Ltab,
                  unsigned long long* __restrict__ gmask)   // [3][widx=nt*2+wq][row]
{
    const int tid = threadIdx.x;
    const int bid = blockIdx.x;
    const int bt = (bid >> 3) & 7;
    const int b0 = bt * 128;                               // batch tile (8)
    const int nt = (bid & 7) | ((bid >> 6) << 3);          // memory tile (512), XCD-grouped
    const int n0 = nt * 128;
    const int lane = tid & 63, wave = tid >> 6;
    const int wm = (wave >> 1) * 64, wn = (wave & 1) * 64;
    const int l15 = lane & 15, l4 = lane >> 4;

    f32x4 acc[4][4] = {};

    // per-wave fragment bases: frag (ks*4 + r) at [(ks*4+r)*64]
    const bf16x8* qw = (const bf16x8*)qs  + (size_t)((bt * 2 + (wave >> 1)) * 32) * 64 + lane;
    const bf16x8* kw = (const bf16x8*)kbf + (size_t)((nt * 2 + (wave &  1)) * 32) * 64 + lane;

    bf16x8 qf[2][4], kf[2][4];
#pragma unroll
    for (int j = 0; j < 4; ++j) { qf[0][j] = qw[j * 64]; kf[0][j] = kw[j * 64]; }

#pragma unroll
    for (int s = 0; s < 8; ++s) {
        const int cur = s & 1;
        if (s < 7) {
#pragma unroll
            for (int j = 0; j < 4; ++j) {
                qf[cur ^ 1][j] = qw[((s + 1) * 4 + j) * 64];
                kf[cur ^ 1][j] = kw[((s + 1) * 4 + j) * 64];
            }
        }
        __builtin_amdgcn_s_setprio(1);
#pragma unroll
        for (int i = 0; i < 4; ++i)
#pragma unroll
            for (int j = 0; j < 4; ++j)
                acc[i][j] = __builtin_amdgcn_mfma_f32_16x16x32_bf16(kf[cur][i], qf[cur][j], acc[i][j], 0, 0, 0);
        __builtin_amdgcn_s_setprio(0);
    }

    // epilogue: within acc[i][j]: mem-bit = i*16 + l4*4 + reg (cols n0+wn+..),
    // batch = b0 + wm + j*16 + l15. Three threshold masks, no value stores.
    float4 Lv[4];
#pragma unroll
    for (int i = 0; i < 4; ++i)
        Lv[i] = *(const float4*)&Ltab[n0 + wn + i * 16 + l4 * 4];
#pragma unroll
    for (int j = 0; j < 4; ++j) {
        const int rb = b0 + wm + j * 16 + l15;
        unsigned int lo0 = 0, hi0 = 0, lo1 = 0, hi1 = 0, lo2 = 0, hi2 = 0;
#pragma unroll
        for (int i = 0; i < 4; ++i) {
            const float* lv = (const float*)&Lv[i];
            unsigned int n0b = 0, n1b = 0, n2b = 0;
#pragma unroll
            for (int reg = 0; reg < 4; ++reg) {
                float x = fmaf(acc[i][j][reg], KSC, lv[reg]);
                n0b |= (x >= T0 ? 1u : 0u) << reg;
                n1b |= (x >= T1 ? 1u : 0u) << reg;
                n2b |= (x >= T2 ? 1u : 0u) << reg;
            }
            const int sh = (i & 1) * 16 + l4 * 4;
            if (i < 2) { lo0 |= n0b << sh; lo1 |= n1b << sh; lo2 |= n2b << sh; }
            else       { hi0 |= n0b << sh; hi1 |= n1b << sh; hi2 |= n2b << sh; }
        }
        lo0 |= __shfl_xor(lo0, 16, 64); hi0 |= __shfl_xor(hi0, 16, 64);
        lo0 |= __shfl_xor(lo0, 32, 64); hi0 |= __shfl_xor(hi0, 32, 64);
        lo1 |= __shfl_xor(lo1, 16, 64); hi1 |= __shfl_xor(hi1, 16, 64);
        lo1 |= __shfl_xor(lo1, 32, 64); hi1 |= __shfl_xor(hi1, 32, 64);
        lo2 |= __shfl_xor(lo2, 16, 64); hi2 |= __shfl_xor(hi2, 16, 64);
        lo2 |= __shfl_xor(lo2, 32, 64); hi2 |= __shfl_xor(hi2, 32, 64);
        if (l4 == 0) {
            // SoA level-major: [lvl][widx = nt*2 + (wn>>6)][row]; 16 l15-lanes
            // store 16 consecutive rows -> 128B contiguous = full lines.
            const size_t ofs = ((size_t)(nt * 2) + (wn >> 6)) * 1024 + rb;
            gmask[ofs]            = ((unsigned long long)hi0 << 32) | lo0;
            gmask[ofs + LVLW]     = ((unsigned long long)hi1 << 32) | lo1;
            gmask[ofs + 2 * LVLW] = ((unsigned long long)hi2 << 32) | lo2;
        }
    }
}

// -------------------------------------------------------------------------
// Kernel 2: per batch row — lazy level reads:
//   read level-2 mask only (8KB scattered 8B words), popcount; if
//   SELK <= cnt <= 1024 (expected ~82% of rows) walk it; else drop to
//   level 1, then level 0 (walk with cap — same risk posture as r15).
//   Walk -> cidx (reserve-range); exact fp32 rescore; count-based exact
//   top-128 (ties -> lower index); weighted sum.
// -------------------------------------------------------------------------
__global__ __launch_bounds__(256, 4)
void select_kernel(const float* __restrict__ q,
                   const float* __restrict__ key,
                   const float* __restrict__ hist,
                   const float* __restrict__ vals,
                   const unsigned long long* __restrict__ gmask,
                   float* __restrict__ out)
{
    const int b   = blockIdx.x;
    const int tid = threadIdx.x;

    __shared__ __align__(16) float qs[KDIM];
    __shared__ int   scal[2];                 // 0: level count  1: listpos
    __shared__ int   cidx[1024];
    __shared__ float csc[1024], cjj[1024], cjv[1024];
    __shared__ float wred[8];

    qs[tid] = q[(size_t)b * KDIM + tid];
    if (tid < 2) scal[tid] = 0;
    __syncthreads();

    // ---- lazy mask read: level 2, then 1, then 0 ----
    unsigned long long mw[4];
    int myc = 0;
    int lvlsel = 2;
    for (;;) {
        myc = 0;
#pragma unroll
        for (int k = 0; k < 4; ++k) {
            mw[k] = gmask[(size_t)lvlsel * LVLW + (size_t)(tid + k * 256) * 1024 + b];
            myc += __popcll(mw[k]);
        }
        { int ws = myc;
#pragma unroll
          for (int off = 32; off > 0; off >>= 1) ws += __shfl_xor(ws, off, 64);
          if ((tid & 63) == 0) atomicAdd((unsigned int*)&scal[0], (unsigned int)ws); }
        __syncthreads();
        const int c = scal[0];
        __syncthreads();
        if ((c >= SELK && c <= 1024) || lvlsel == 0) break;
        if (tid == 0) scal[0] = 0;
        __syncthreads();
        --lvlsel;
    }

    // ---- walk mask -> cidx (reserve-range; order-independent) ----
    int base = atomicAdd(&scal[1], myc);
#pragma unroll
    for (int k = 0; k < 4; ++k) {
        unsigned long long m = mw[k];
        while (m) {
            int bpos = __builtin_ctzll(m);
            m &= m - 1;
            if (base < 1024) cidx[base] = (tid + k * 256) * 64 + bpos;
            ++base;
        }
    }
    __syncthreads();
    const int ncand = min(scal[1], 1024);

    // ---- exact fp32 rescore: 16-lane groups, 4 candidates per wave in flight ----
    const int gid = tid >> 4, gll = tid & 15;
    const float4* q4 = (const float4*)qs;
    for (int i = gid; i < ncand; i += 16) {
        const int idx = cidx[i];
        const float4* kp = (const float4*)(key + (size_t)idx * KDIM);
        float p = 0.f;
#pragma unroll
        for (int u = 0; u < 4; ++u) {
            float4 kk = kp[gll * 4 + u];
            float4 qq = q4[gll * 4 + u];
            p += kk.x * qq.x + kk.y * qq.y + kk.z * qq.z + kk.w * qq.w;
        }
#pragma unroll
        for (int off = 1; off < 16; off <<= 1) p += __shfl_xor(p, off, 64);
        if (gll == 0) {
            float e = expf(p - 1.0f);
            float h = hist[idx];
            csc[i] = e * (h + BETA);
            float j = e * (ALPHA * h + BETA);
            cjj[i] = j;
            cjv[i] = j * vals[idx];
        }
    }
    __syncthreads();

    // ---- exact top-128 among candidates (count-based; ties -> lower index) ----
    const int wave = tid >> 6, lane = tid & 63;
    float pn = 0.f, pd = 0.f;
    for (int i = tid; i < ncand; i += 256) {
        float si = csc[i]; int ii = cidx[i]; int rank = 0;
        for (int t = 0; t < ncand; ++t) {
            float st = csc[t];
            rank += (st > si || (st == si && cidx[t] < ii)) ? 1 : 0;
        }
        if (rank < CHOOSEK) { pn += cjv[i]; pd += cjj[i]; }
    }
#pragma unroll
    for (int off = 32; off > 0; off >>= 1) {
        pn += __shfl_xor(pn, off, 64);
        pd += __shfl_xor(pd, off, 64);
    }
    if (lane == 0) { wred[wave] = pn; wred[4 + wave] = pd; }
    __syncthreads();
    if (tid == 0) {
        float n = wred[0] + wred[1] + wred[2] + wred[3];
        float d = wred[4] + wred[5] + wred[6] + wred[7];
        out[b] = n / d;
    }
}

// -------------------------------------------------------------------------
extern "C" void kernel_launch(void* const* d_in, const int* in_sizes, int n_in,
                              void* d_out, int out_size, void* d_ws, size_t ws_size,
                              hipStream_t stream)
{
    (void)in_sizes; (void)n_in; (void)out_size; (void)ws_size;
    const float* q    = (const float*)d_in[0];
    const float* key  = (const float*)d_in[1];
    const float* hist = (const float*)d_in[2];
    const float* vals = (const float*)d_in[3];
    float* out = (float*)d_out;

    // workspace layout (57 MiB total):
    unsigned short* kbf= (unsigned short*)d_ws;                                    // 32 MiB bf16 key (B-frag order)
    unsigned short* qsw= (unsigned short*)((char*)d_ws + ((size_t)32 << 20));      // 512 KiB bf16 q (A-frag order)
    float*          Lt = (float*)((char*)d_ws + ((size_t)32 << 20) + (512 << 10)); // 256 KiB L table
    unsigned long long* gmask = (unsigned long long*)((char*)d_ws + ((size_t)33 << 20)); // 3 x 8 MiB masks (SoA)

    convert_kernel<<<8576, 256, 0, stream>>>(q, key, hist, qsw, kbf, Lt);
    score_kernel<<<4096, 256, 0, stream>>>(qsw, kbf, Lt, gmask);
    select_kernel<<<BATCH, 256, 0, stream>>>(q, key, hist, vals, gmask, out);
}

// Round 17
// 182.820 us; speedup vs baseline: 1.0597x; 1.0597x over previous
//
#include <hip/hip_runtime.h>

#define BATCH   1024
#define MSIZE   65536
#define KDIM    256
#define CHOOSEK 128
#define SELK    160        // superset floor (margin vs bf16 screening error, proven r2-r16)
// Three mask thresholds on the u8-scale screened score x = sim*KSC + L[n]:
// cnt(>=156)~307+-17, cnt(>=160)~230+-15, cnt(>=164)~172+-13 (model validated at
// 128 -> ~1650-2800 obs, 152 -> ~410). Select walks the HIGHEST level with
// SELK <= cnt <= 1024: |{x>=T}| >= SELK ==> {x>=T} superset of screened-top-SELK
// superset of exact top-128; extra candidates never alter the exact-rescored top-128.
#define T0  156.0f
#define T1  160.0f
#define T2  164.0f
#define BETA    1e-8f
#define ALPHA   0.5f
#define KSC  425.0f
#define KOFF 7.2f
#define LVLW ((size_t)1024 * 1024)   // u64 words per mask level (1024 widx x 1024 rows)

typedef short bf16x8 __attribute__((ext_vector_type(8)));
typedef float f32x4  __attribute__((ext_vector_type(4)));

__device__ inline unsigned int pack2bf(float a, float b) {   // RNE fp32->bf16 pair
    unsigned int ua = __float_as_uint(a);
    unsigned int ub = __float_as_uint(b);
    ua += 0x7fffu + ((ua >> 16) & 1u);
    ub += 0x7fffu + ((ub >> 16) & 1u);
    return (ua >> 16) | (ub & 0xffff0000u);
}

// -------------------------------------------------------------------------
// Kernel 0: one-time preprocessing (unchanged from r16).
// -------------------------------------------------------------------------
__global__ __launch_bounds__(256)
void convert_kernel(const float* __restrict__ q, const float* __restrict__ key,
                    const float* __restrict__ hist,
                    unsigned short* __restrict__ qs, unsigned short* __restrict__ kbf,
                    float* __restrict__ Ltab)
{
    const int bid = blockIdx.x, tid = threadIdx.x;
    if (bid < 8192) {                       // key -> B-fragment order
        const int t = bid * 256 + tid;      // frag = t>>6, lane = t&63
        const int l = t & 63, f = t >> 6;
        const int i = f & 3, ks = (f >> 2) & 7, wnh = (f >> 5) & 1, nt = f >> 6;
        const int row = nt * 128 + wnh * 64 + i * 16 + (l & 15);
        const int col = ks * 32 + (l >> 4) * 8;
        const float* src = key + (size_t)row * KDIM + col;
        float4 a = *(const float4*)src, b = *(const float4*)(src + 4);
        ((uint4*)kbf)[t] = make_uint4(pack2bf(a.x, a.y), pack2bf(a.z, a.w),
                                      pack2bf(b.x, b.y), pack2bf(b.z, b.w));
    } else if (bid < 8320) {                // q -> A-fragment order (128-row tiles)
        const int f = (bid - 8192) * 256 + tid;
        const int l = f & 63, j = (f >> 6) & 3, ks = (f >> 8) & 7;
        const int wmg = (f >> 11) & 1, bt = f >> 12;       // bt in [0,8)
        const int r = bt * 128 + wmg * 64 + j * 16 + (l & 15);
        const int c = ks * 32 + (l >> 4) * 8;
        const float* src = q + (size_t)r * KDIM + c;
        float4 a = *(const float4*)src, b = *(const float4*)(src + 4);
        ((uint4*)qs)[f] = make_uint4(pack2bf(a.x, a.y), pack2bf(a.z, a.w),
                                     pack2bf(b.x, b.y), pack2bf(b.z, b.w));
    } else {                                // L table
        const int n = (bid - 8320) * 256 + tid;
        Ltab[n] = (logf(hist[n] + BETA) + KOFF) * KSC;
    }
}

// -------------------------------------------------------------------------
// Kernel 1: BARRIER-FREE bf16 screening GEMM (r16 K-loop, verified 50.8us).
// Epilogue changed: mask word bit-order PERMUTED so each lane's 16 bits are
// contiguous (bit p = l4*16 + i*4 + reg). Every lane stores its own u16 —
// no shfl OR-reduce, no lane predication; 64 lanes x 2B = one contiguous
// 128B segment per (j,level). Select decodes col from p.
// -------------------------------------------------------------------------
__global__ __launch_bounds__(256)
void score_kernel(const unsigned short* __restrict__ qs,
                  const unsigned short* __restrict__ kbf,
                  const float* __restrict__ Ltab,
                  unsigned short* __restrict__ gm16)   // u16 view of [3][widx][row] u64 masks
{
    const int tid = threadIdx.x;
    const int bid = blockIdx.x;
    const int bt = (bid >> 3) & 7;
    const int b0 = bt * 128;                               // batch tile (8)
    const int nt = (bid & 7) | ((bid >> 6) << 3);          // memory tile (512), XCD-grouped
    const int n0 = nt * 128;
    const int lane = tid & 63, wave = tid >> 6;
    const int wm = (wave >> 1) * 64, wn = (wave & 1) * 64;
    const int l15 = lane & 15, l4 = lane >> 4;
    const int widx = nt * 2 + (wave & 1);

    f32x4 acc[4][4] = {};

    // per-wave fragment bases: frag (ks*4 + r) at [(ks*4+r)*64]
    const bf16x8* qw = (const bf16x8*)qs  + (size_t)((bt * 2 + (wave >> 1)) * 32) * 64 + lane;
    const bf16x8* kw = (const bf16x8*)kbf + (size_t)((nt * 2 + (wave &  1)) * 32) * 64 + lane;

    bf16x8 qf[2][4], kf[2][4];
#pragma unroll
    for (int j = 0; j < 4; ++j) { qf[0][j] = qw[j * 64]; kf[0][j] = kw[j * 64]; }

#pragma unroll
    for (int s = 0; s < 8; ++s) {
        const int cur = s & 1;
        if (s < 7) {
#pragma unroll
            for (int j = 0; j < 4; ++j) {
                qf[cur ^ 1][j] = qw[((s + 1) * 4 + j) * 64];
                kf[cur ^ 1][j] = kw[((s + 1) * 4 + j) * 64];
            }
        }
        __builtin_amdgcn_s_setprio(1);
#pragma unroll
        for (int i = 0; i < 4; ++i)
#pragma unroll
            for (int j = 0; j < 4; ++j)
                acc[i][j] = __builtin_amdgcn_mfma_f32_16x16x32_bf16(kf[cur][i], qf[cur][j], acc[i][j], 0, 0, 0);
        __builtin_amdgcn_s_setprio(0);
    }

    // epilogue: acc[i][j] covers cols n0+wn+i*16+l4*4+reg, row b0+wm+j*16+l15.
    // Lane's 16 bits (i*4+reg) stored as its own u16 at piece index l4.
    float4 Lv[4];
#pragma unroll
    for (int i = 0; i < 4; ++i)
        Lv[i] = *(const float4*)&Ltab[n0 + wn + i * 16 + l4 * 4];
#pragma unroll
    for (int j = 0; j < 4; ++j) {
        const int rb = b0 + wm + j * 16 + l15;
        unsigned int p0 = 0, p1 = 0, p2 = 0;
#pragma unroll
        for (int i = 0; i < 4; ++i) {
            const float* lv = (const float*)&Lv[i];
#pragma unroll
            for (int reg = 0; reg < 4; ++reg) {
                float x = fmaf(acc[i][j][reg], KSC, lv[reg]);
                p0 |= (x >= T0 ? 1u : 0u) << (i * 4 + reg);
                p1 |= (x >= T1 ? 1u : 0u) << (i * 4 + reg);
                p2 |= (x >= T2 ? 1u : 0u) << (i * 4 + reg);
            }
        }
        const size_t u16i = ((size_t)widx * 1024 + rb) * 4 + l4;
        gm16[u16i]                = (unsigned short)p0;
        gm16[u16i + LVLW * 4]     = (unsigned short)p1;
        gm16[u16i + 2 * LVLW * 4] = (unsigned short)p2;
    }
}

// -------------------------------------------------------------------------
// Kernel 2: per batch row. XCD-GROUPED row mapping (r16 lesson: round-robin
// dispatch put adjacent rows on different XCDs -> each XCD's L2 fetched the
// same mask line separately, FETCH 92MB). row = (bid&7)*128 + bid>>3 gives
// XCD x the contiguous rows [128x,128x+128) -> every mask line consumed
// within one L2. Lazy level reads (2 -> 1 -> 0); walk decodes permuted bit
// order: col = ((p>>2)&3)*16 + (p>>4)*4 + (p&3). Rescore + exact top-128.
// -------------------------------------------------------------------------
__global__ __launch_bounds__(256, 4)
void select_kernel(const float* __restrict__ q,
                   const float* __restrict__ key,
                   const float* __restrict__ hist,
                   const float* __restrict__ vals,
                   const unsigned long long* __restrict__ gmask,
                   float* __restrict__ out)
{
    const int bid = blockIdx.x;
    const int b   = ((bid & 7) << 7) | (bid >> 3);   // XCD-grouped row mapping
    const int tid = threadIdx.x;

    __shared__ __align__(16) float qs[KDIM];
    __shared__ int   scal[2];                 // 0: level count  1: listpos
    __shared__ int   cidx[1024];
    __shared__ float csc[1024], cjj[1024], cjv[1024];
    __shared__ float wred[8];

    qs[tid] = q[(size_t)b * KDIM + tid];
    if (tid < 2) scal[tid] = 0;
    __syncthreads();

    // ---- lazy mask read: level 2, then 1, then 0 ----
    unsigned long long mw[4];
    int myc = 0;
    int lvlsel = 2;
    for (;;) {
        myc = 0;
#pragma unroll
        for (int k = 0; k < 4; ++k) {
            mw[k] = gmask[(size_t)lvlsel * LVLW + (size_t)(tid + k * 256) * 1024 + b];
            myc += __popcll(mw[k]);
        }
        { int ws = myc;
#pragma unroll
          for (int off = 32; off > 0; off >>= 1) ws += __shfl_xor(ws, off, 64);
          if ((tid & 63) == 0) atomicAdd((unsigned int*)&scal[0], (unsigned int)ws); }
        __syncthreads();
        const int c = scal[0];
        __syncthreads();
        if ((c >= SELK && c <= 1024) || lvlsel == 0) break;
        if (tid == 0) scal[0] = 0;
        __syncthreads();
        --lvlsel;
    }

    // ---- walk mask -> cidx (reserve-range; order-independent) ----
    int base = atomicAdd(&scal[1], myc);
#pragma unroll
    for (int k = 0; k < 4; ++k) {
        unsigned long long m = mw[k];
        while (m) {
            int p = __builtin_ctzll(m);
            m &= m - 1;
            // permuted bit order: p = l4*16 + i*4 + reg -> col = i*16 + l4*4 + reg
            int col = ((p >> 2) & 3) * 16 + ((p >> 4) << 2) + (p & 3);
            if (base < 1024) cidx[base] = (tid + k * 256) * 64 + col;
            ++base;
        }
    }
    __syncthreads();
    const int ncand = min(scal[1], 1024);

    // ---- exact fp32 rescore: 16-lane groups, 4 candidates per wave in flight ----
    const int gid = tid >> 4, gll = tid & 15;
    const float4* q4 = (const float4*)qs;
    for (int i = gid; i < ncand; i += 16) {
        const int idx = cidx[i];
        const float4* kp = (const float4*)(key + (size_t)idx * KDIM);
        float p = 0.f;
#pragma unroll
        for (int u = 0; u < 4; ++u) {
            float4 kk = kp[gll * 4 + u];
            float4 qq = q4[gll * 4 + u];
            p += kk.x * qq.x + kk.y * qq.y + kk.z * qq.z + kk.w * qq.w;
        }
#pragma unroll
        for (int off = 1; off < 16; off <<= 1) p += __shfl_xor(p, off, 64);
        if (gll == 0) {
            float e = expf(p - 1.0f);
            float h = hist[idx];
            csc[i] = e * (h + BETA);
            float j = e * (ALPHA * h + BETA);
            cjj[i] = j;
            cjv[i] = j * vals[idx];
        }
    }
    __syncthreads();

    // ---- exact top-128 among candidates (count-based; ties -> lower index) ----
    const int wave = tid >> 6, lane = tid & 63;
    float pn = 0.f, pd = 0.f;
    for (int i = tid; i < ncand; i += 256) {
        float si = csc[i]; int ii = cidx[i]; int rank = 0;
        for (int t = 0; t < ncand; ++t) {
            float st = csc[t];
            rank += (st > si || (st == si && cidx[t] < ii)) ? 1 : 0;
        }
        if (rank < CHOOSEK) { pn += cjv[i]; pd += cjj[i]; }
    }
#pragma unroll
    for (int off = 32; off > 0; off >>= 1) {
        pn += __shfl_xor(pn, off, 64);
        pd += __shfl_xor(pd, off, 64);
    }
    if (lane == 0) { wred[wave] = pn; wred[4 + wave] = pd; }
    __syncthreads();
    if (tid == 0) {
        float n = wred[0] + wred[1] + wred[2] + wred[3];
        float d = wred[4] + wred[5] + wred[6] + wred[7];
        out[b] = n / d;
    }
}

// -------------------------------------------------------------------------
extern "C" void kernel_launch(void* const* d_in, const int* in_sizes, int n_in,
                              void* d_out, int out_size, void* d_ws, size_t ws_size,
                              hipStream_t stream)
{
    (void)in_sizes; (void)n_in; (void)out_size; (void)ws_size;
    const float* q    = (const float*)d_in[0];
    const float* key  = (const float*)d_in[1];
    const float* hist = (const float*)d_in[2];
    const float* vals = (const float*)d_in[3];
    float* out = (float*)d_out;

    // workspace layout (57 MiB total):
    unsigned short* kbf= (unsigned short*)d_ws;                                    // 32 MiB bf16 key (B-frag order)
    unsigned short* qsw= (unsigned short*)((char*)d_ws + ((size_t)32 << 20));      // 512 KiB bf16 q (A-frag order)
    float*          Lt = (float*)((char*)d_ws + ((size_t)32 << 20) + (512 << 10)); // 256 KiB L table
    unsigned long long* gmask = (unsigned long long*)((char*)d_ws + ((size_t)33 << 20)); // 3 x 8 MiB masks (SoA)

    convert_kernel<<<8576, 256, 0, stream>>>(q, key, hist, qsw, kbf, Lt);
    score_kernel<<<4096, 256, 0, stream>>>(qsw, kbf, Lt, (unsigned short*)gmask);
    select_kernel<<<BATCH, 256, 0, stream>>>(q, key, hist, vals, gmask, out);
}